// Round 11
// baseline (1114.090 us; speedup 1.0000x reference)
//
#include <hip/hip_runtime.h>
#include <cstddef>

#define BATCH 4
#define NPTS 4096
#define KNN 32

__device__ __forceinline__ float leaky(float v) { return v >= 0.f ? v : 0.2f * v; }

// monotone float->uint encoding: larger float => larger uint
__device__ __forceinline__ unsigned encf(float f) {
    unsigned b = __float_as_uint(f);
    return (b & 0x80000000u) ? ~b : (b | 0x80000000u);
}
__device__ __forceinline__ float decf(unsigned e) {
    unsigned b = (e & 0x80000000u) ? (e ^ 0x80000000u) : ~e;
    return __uint_as_float(b);
}
__device__ __forceinline__ unsigned umaxu(unsigned a, unsigned b) { return a > b ? a : b; }

// DPP wave-wide unsigned max; result wave-uniform via readlane 63 -> SGPR.
__device__ __forceinline__ unsigned wave_umax_bcast(unsigned v) {
    int x = (int)v, t;
    t = __builtin_amdgcn_update_dpp(0, x, 0x111, 0xF, 0xF, true); x = (int)umaxu((unsigned)x, (unsigned)t);
    t = __builtin_amdgcn_update_dpp(0, x, 0x112, 0xF, 0xF, true); x = (int)umaxu((unsigned)x, (unsigned)t);
    t = __builtin_amdgcn_update_dpp(0, x, 0x114, 0xF, 0xF, true); x = (int)umaxu((unsigned)x, (unsigned)t);
    t = __builtin_amdgcn_update_dpp(0, x, 0x118, 0xF, 0xF, true); x = (int)umaxu((unsigned)x, (unsigned)t);
    t = __builtin_amdgcn_update_dpp(0, x, 0x142, 0xA, 0xF, true); x = (int)umaxu((unsigned)x, (unsigned)t);
    t = __builtin_amdgcn_update_dpp(0, x, 0x143, 0xC, 0xF, true); x = (int)umaxu((unsigned)x, (unsigned)t);
    return (unsigned)__builtin_amdgcn_readlane(x, 63);
}

// ---------------- one extraction step, v3: cached m8 + bitmask winner ----------------
// u[64]: lane's values (STATIC indexing only). g[8]: group maxima. m8: cached max(g)
// (only the winner's m8 changes, so it is kept across steps instead of recomputed
// wave-wide — R10 fix for the ~170-instr/step winner-scan cost).
template <int CM>
__device__ __forceinline__ void extract_step_reg(unsigned* u, unsigned* g, unsigned& m8,
                                                 int lane, int* __restrict__ outp, int it) {
    unsigned wm = wave_umax_bcast(m8);
    unsigned long long msk = __ballot(m8 == wm);
    int wl = __ffsll(msk) - 1;
    if (lane == wl) {
        unsigned gmask = 0;
        #pragma unroll
        for (int G = 0; G < 8; ++G) gmask |= (g[G] == wm ? 1u : 0u) << G;
        int gi = __ffs(gmask) - 1;
        int sq = 0;
        #pragma unroll
        for (int G = 0; G < 8; ++G) {
            if (G == gi) {   // exactly one body runs; others skip via execz
                unsigned qm = 0;
                #pragma unroll
                for (int q = 0; q < 8; ++q) qm |= (u[G * 8 + q] == wm ? 1u : 0u) << q;
                int q0 = __ffs(qm) - 1;
                #pragma unroll
                for (int q = 0; q < 8; ++q) u[G * 8 + q] = (q == q0) ? 0u : u[G * 8 + q];
                unsigned ng = 0;
                #pragma unroll
                for (int q = 0; q < 8; ++q) ng = umaxu(ng, u[G * 8 + q]);
                g[G] = ng;
                sq = G * 8 + q0;
            }
        }
        m8 = umaxu(umaxu(umaxu(g[0], g[1]), umaxu(g[2], g[3])),
                   umaxu(umaxu(g[4], g[5]), umaxu(g[6], g[7])));
        int col;
        if (CM == 0) col = ((sq >> 2) << 8) + (lane << 2) + (sq & 3);
        else col = (sq << 6) + lane;
        outp[it] = col;
    }
}

// ---------------- transpose x (B,8,N) -> xcl (B,N,8) ----------------
__global__ __launch_bounds__(256) void txcl_kernel(const float* __restrict__ x,
                                                   float* __restrict__ xcl) {
    int i = blockIdx.x * 256 + threadIdx.x;
    int n = i & 4095;
    int c = (i >> 12) & 7;
    int b = i >> 15;
    xcl[(size_t)(b * NPTS + n) * 8 + c] = x[i];
}

// ---------------- KNN on 2-d coords: no LDS, values in VGPRs, 1 row/wave ----------------
__global__ __launch_bounds__(256, 4) void knn1_kernel(const float* __restrict__ x,
                                                      int* __restrict__ idxo) {
    int t = threadIdx.x, w = t >> 6, lane = t & 63;
    int b = blockIdx.y;
    int row = blockIdx.x * 4 + w;
    const float* px = x + (size_t)b * 8 * NPTS + 6 * NPTS;
    const float* py = px + NPTS;
    float xr = px[row], yr = py[row];
    unsigned u[64];
    unsigned g[8];
    #pragma unroll
    for (int i = 0; i < 8; ++i) g[i] = 0u;
    #pragma unroll
    for (int j = 0; j < 64; ++j) {
        int col = (j << 6) + lane;
        float xm = px[col], ym = py[col];
        float v = 2.f * (xr * xm + yr * ym) - (xm * xm + ym * ym);
        unsigned e = encf(v);
        u[j] = e;
        g[j >> 3] = umaxu(g[j >> 3], e);
    }
    unsigned m8 = umaxu(umaxu(umaxu(g[0], g[1]), umaxu(g[2], g[3])),
                        umaxu(umaxu(g[4], g[5]), umaxu(g[6], g[7])));
    int* outp = idxo + ((size_t)(b * NPTS + row) << 5);
    for (int it = 0; it < 32; ++it)
        extract_step_reg<1>(u, g, m8, lane, outp, it);
}

// ---------------- distance GEMM; batch = b0 + blockIdx.y, E slab per blockIdx.y ----------------
__global__ __launch_bounds__(256) void dist_gemm_kernel(const float* __restrict__ feat,
                                                        const float* __restrict__ xx,
                                                        unsigned* __restrict__ E0,
                                                        int b0, unsigned long long estride) {
    int bi = blockIdx.x >> 5, bj = blockIdx.x & 31;
    if (bi > bj) return;
    unsigned* E = E0 + (size_t)blockIdx.y * estride;
    int b = b0 + blockIdx.y;
    __shared__ __align__(16) float As[16][132];
    __shared__ __align__(16) float Bs[16][192];
    int t = threadIdx.x;
    int tx = t & 15, ty = t >> 4;
    const float* fb = feat + (size_t)b * NPTS * 64;
    const float* xb = xx + b * NPTS;
    int m0 = bi * 128, n0 = bj * 128;
    float acc[8][8];
    #pragma unroll
    for (int r = 0; r < 8; ++r)
        #pragma unroll
        for (int c = 0; c < 8; ++c) acc[r][c] = 0.f;
    int sm = t >> 1;
    int sk0 = (t & 1) * 8;
    int bc = (sm >> 3) * 12 + (sm & 7);
    for (int k0 = 0; k0 < 64; k0 += 16) {
        float4 a0 = *(const float4*)&fb[(size_t)(m0 + sm) * 64 + k0 + sk0];
        float4 a1 = *(const float4*)&fb[(size_t)(m0 + sm) * 64 + k0 + sk0 + 4];
        float4 b0v = *(const float4*)&fb[(size_t)(n0 + sm) * 64 + k0 + sk0];
        float4 b1v = *(const float4*)&fb[(size_t)(n0 + sm) * 64 + k0 + sk0 + 4];
        __syncthreads();
        As[sk0 + 0][sm] = a0.x; As[sk0 + 1][sm] = a0.y; As[sk0 + 2][sm] = a0.z; As[sk0 + 3][sm] = a0.w;
        As[sk0 + 4][sm] = a1.x; As[sk0 + 5][sm] = a1.y; As[sk0 + 6][sm] = a1.z; As[sk0 + 7][sm] = a1.w;
        Bs[sk0 + 0][bc] = b0v.x; Bs[sk0 + 1][bc] = b0v.y; Bs[sk0 + 2][bc] = b0v.z; Bs[sk0 + 3][bc] = b0v.w;
        Bs[sk0 + 4][bc] = b1v.x; Bs[sk0 + 5][bc] = b1v.y; Bs[sk0 + 6][bc] = b1v.z; Bs[sk0 + 7][bc] = b1v.w;
        __syncthreads();
        #pragma unroll
        for (int kk = 0; kk < 16; ++kk) {
            float4 av0 = *(const float4*)&As[kk][ty * 8];
            float4 av1 = *(const float4*)&As[kk][ty * 8 + 4];
            float4 bv0 = *(const float4*)&Bs[kk][tx * 12];
            float4 bv1 = *(const float4*)&Bs[kk][tx * 12 + 4];
            float av[8] = {av0.x, av0.y, av0.z, av0.w, av1.x, av1.y, av1.z, av1.w};
            float bv[8] = {bv0.x, bv0.y, bv0.z, bv0.w, bv1.x, bv1.y, bv1.z, bv1.w};
            #pragma unroll
            for (int r = 0; r < 8; ++r)
                #pragma unroll
                for (int c = 0; c < 8; ++c) acc[r][c] += av[r] * bv[c];
        }
    }
    float xxj[8], xxi[8];
    #pragma unroll
    for (int c = 0; c < 8; ++c) xxj[c] = xb[n0 + tx * 8 + c];
    #pragma unroll
    for (int r = 0; r < 8; ++r) xxi[r] = xb[m0 + ty * 8 + r];
    #pragma unroll
    for (int r = 0; r < 8; ++r) {
        uint4 e0, e1;
        e0.x = encf(2.f * acc[r][0] - xxj[0]); e0.y = encf(2.f * acc[r][1] - xxj[1]);
        e0.z = encf(2.f * acc[r][2] - xxj[2]); e0.w = encf(2.f * acc[r][3] - xxj[3]);
        e1.x = encf(2.f * acc[r][4] - xxj[4]); e1.y = encf(2.f * acc[r][5] - xxj[5]);
        e1.z = encf(2.f * acc[r][6] - xxj[6]); e1.w = encf(2.f * acc[r][7] - xxj[7]);
        size_t ro = ((size_t)(m0 + ty * 8 + r) << 12) + n0 + tx * 8;
        *(uint4*)&E[ro] = e0;
        *(uint4*)&E[ro + 4] = e1;
    }
    if (bi != bj) {
        #pragma unroll
        for (int c = 0; c < 8; ++c) {
            uint4 e0, e1;
            e0.x = encf(2.f * acc[0][c] - xxi[0]); e0.y = encf(2.f * acc[1][c] - xxi[1]);
            e0.z = encf(2.f * acc[2][c] - xxi[2]); e0.w = encf(2.f * acc[3][c] - xxi[3]);
            e1.x = encf(2.f * acc[4][c] - xxi[4]); e1.y = encf(2.f * acc[5][c] - xxi[5]);
            e1.z = encf(2.f * acc[6][c] - xxi[6]); e1.w = encf(2.f * acc[7][c] - xxi[7]);
            size_t ro = ((size_t)(n0 + tx * 8 + c) << 12) + m0 + ty * 8;
            *(uint4*)&E[ro] = e0;
            *(uint4*)&E[ro + 4] = e1;
        }
    }
}

// ---------------- select top-32/row from E; batch = b0 + blockIdx.y ----------------
__global__ __launch_bounds__(256, 4) void knn_select_kernel(const unsigned* __restrict__ E0,
                                                            int* __restrict__ idxo,
                                                            int b0, unsigned long long estride) {
    const unsigned* E = E0 + (size_t)blockIdx.y * estride;
    int b = b0 + blockIdx.y;
    int t = threadIdx.x, w = t >> 6, lane = t & 63;
    int row = blockIdx.x * 4 + w;
    const uint4* Er = (const uint4*)(E + ((size_t)row << 12));
    unsigned u[64];
    unsigned g[8];
    #pragma unroll
    for (int i = 0; i < 8; ++i) g[i] = 0u;
    #pragma unroll
    for (int i = 0; i < 16; ++i) {
        uint4 v = Er[i * 64 + lane];
        u[4 * i + 0] = v.x;
        u[4 * i + 1] = v.y;
        u[4 * i + 2] = v.z;
        u[4 * i + 3] = v.w;
        g[i >> 1] = umaxu(g[i >> 1], umaxu(umaxu(v.x, v.y), umaxu(v.z, v.w)));
    }
    unsigned m8 = umaxu(umaxu(umaxu(g[0], g[1]), umaxu(g[2], g[3])),
                        umaxu(umaxu(g[4], g[5]), umaxu(g[6], g[7])));
    int* outp = idxo + ((size_t)(b * NPTS + row) << 5);
    for (int it = 0; it < 32; ++it)
        extract_step_reg<0>(u, g, m8, lane, outp, it);
}

// ---------------- qpre: P[m][o]=Wlo.f_m (o<64), P[m][64+o]=(Whi-Wlo).f_m ----------------
template <int KC>
__global__ __launch_bounds__(256) void qpre_kernel(const float* __restrict__ f,
                                                   const float* __restrict__ W,
                                                   float* __restrict__ P) {
    int t = threadIdx.x, w = t >> 6, lane = t & 63;
    float wlo[KC], wd[KC];
    #pragma unroll
    for (int c = 0; c < KC; c += 4) {
        float4 lo = *(const float4*)&W[lane * 2 * KC + c];
        float4 hi = *(const float4*)&W[lane * 2 * KC + KC + c];
        wlo[c] = lo.x; wlo[c + 1] = lo.y; wlo[c + 2] = lo.z; wlo[c + 3] = lo.w;
        wd[c] = hi.x - lo.x; wd[c + 1] = hi.y - lo.y; wd[c + 2] = hi.z - lo.z; wd[c + 3] = hi.w - lo.w;
    }
    int base = blockIdx.x * 32 + w * 8;
    for (int p = 0; p < 8; ++p) {
        int m = base + p;
        const float* fr = f + (size_t)m * KC;
        float alo = 0.f, ad = 0.f;
        #pragma unroll
        for (int c = 0; c < KC; c += 4) {
            float4 fv = *(const float4*)&fr[c];
            alo += wlo[c] * fv.x + wlo[c + 1] * fv.y + wlo[c + 2] * fv.z + wlo[c + 3] * fv.w;
            ad += wd[c] * fv.x + wd[c + 1] * fv.y + wd[c + 2] * fv.z + wd[c + 3] * fv.w;
        }
        P[(size_t)m * 128 + lane] = alo;
        P[(size_t)m * 128 + 64 + lane] = ad;
    }
}

// ---------------- edge layer as tiled GEMM (R9 structure, unchanged) ----------------
__global__ __launch_bounds__(256) void edge_mm_kernel(const float* __restrict__ P,
                                                      const int* __restrict__ idx,
                                                      const float* __restrict__ sA,
                                                      const float* __restrict__ bA,
                                                      const float* __restrict__ W2,
                                                      const float* __restrict__ sB,
                                                      const float* __restrict__ bB,
                                                      float* __restrict__ xo,
                                                      float* __restrict__ xxo) {
    __shared__ __align__(16) float h1T[64][132];
    __shared__ __align__(16) float Bs[64][68];
    __shared__ __align__(16) float pdd_s[4][64];
    __shared__ float scA_s[64], biA_s[64];
    __shared__ int ids[128];
    int t = threadIdx.x;
    int b = blockIdx.y;
    int n0 = blockIdx.x * 4;
    if (t < 128) ids[t] = idx[((size_t)(b * NPTS + n0 + (t >> 5))) * KNN + (t & 31)];
    else if (t < 192) scA_s[t - 128] = sA[t - 128];
    else biA_s[t - 192] = bA[t - 192];
    pdd_s[t >> 6][t & 63] = P[((size_t)(b * NPTS + n0 + (t >> 6))) * 128 + 64 + (t & 63)];
    __syncthreads();
    {
        int o = t & 63, kk0 = (t >> 6) * 16;
        #pragma unroll
        for (int j = 0; j < 16; j += 4) {
            float4 v = *(const float4*)&W2[o * 64 + kk0 + j];
            Bs[kk0 + j + 0][o] = v.x;
            Bs[kk0 + j + 1][o] = v.y;
            Bs[kk0 + j + 2][o] = v.z;
            Bs[kk0 + j + 3][o] = v.w;
        }
    }
    #pragma unroll
    for (int p = 0; p < 2; ++p) {
        int row = p * 64 + (t >> 2);
        int w = row >> 5;
        int id = ids[row];
        int q = t & 3;
        const float* src = &P[((size_t)(b * NPTS + id)) * 128 + q * 16];
        #pragma unroll
        for (int j = 0; j < 4; ++j) {
            int c = q * 16 + j * 4;
            float4 v = *(const float4*)&src[j * 4];
            float4 sa = *(const float4*)&scA_s[c];
            float4 ba = *(const float4*)&biA_s[c];
            float4 pd = *(const float4*)&pdd_s[w][c];
            h1T[c + 0][row] = leaky(sa.x * (v.x + pd.x) + ba.x);
            h1T[c + 1][row] = leaky(sa.y * (v.y + pd.y) + ba.y);
            h1T[c + 2][row] = leaky(sa.z * (v.z + pd.z) + ba.z);
            h1T[c + 3][row] = leaky(sa.w * (v.w + pd.w) + ba.w);
        }
    }
    __syncthreads();
    int tx = t & 15, ty = t >> 4;
    float acc[8][4];
    #pragma unroll
    for (int r = 0; r < 8; ++r)
        #pragma unroll
        for (int c = 0; c < 4; ++c) acc[r][c] = 0.f;
    #pragma unroll 4
    for (int kk = 0; kk < 64; ++kk) {
        float4 a0 = *(const float4*)&h1T[kk][ty * 8];
        float4 a1 = *(const float4*)&h1T[kk][ty * 8 + 4];
        float4 bb = *(const float4*)&Bs[kk][tx * 4];
        float av[8] = {a0.x, a0.y, a0.z, a0.w, a1.x, a1.y, a1.z, a1.w};
        #pragma unroll
        for (int r = 0; r < 8; ++r) {
            acc[r][0] += av[r] * bb.x;
            acc[r][1] += av[r] * bb.y;
            acc[r][2] += av[r] * bb.z;
            acc[r][3] += av[r] * bb.w;
        }
    }
    float rm[4];
    #pragma unroll
    for (int c = 0; c < 4; ++c) {
        float m = acc[0][c];
        #pragma unroll
        for (int r = 1; r < 8; ++r) m = fmaxf(m, acc[r][c]);
        rm[c] = m;
    }
    __syncthreads();
    float (*red)[68] = Bs;
    #pragma unroll
    for (int c = 0; c < 4; ++c) red[ty][tx * 4 + c] = rm[c];
    __syncthreads();
    int w = t >> 6, lane = t & 63;
    float m = fmaxf(fmaxf(red[4 * w + 0][lane], red[4 * w + 1][lane]),
                    fmaxf(red[4 * w + 2][lane], red[4 * w + 3][lane]));
    float outv = leaky(sB[lane] * m + bB[lane]);
    xo[((size_t)(b * NPTS + n0 + w)) * 64 + lane] = outv;
    if (xxo != nullptr) {
        float sq = outv * outv;
        #pragma unroll
        for (int d = 32; d; d >>= 1) sq += __shfl_xor(sq, d, 64);
        if (lane == 0) xxo[b * NPTS + n0 + w] = sq;
    }
}

// ---------------- edge layer 3: gather + max, activation hoisted (s5>0) ----------------
__global__ __launch_bounds__(256) void edge3_g_kernel(const float* __restrict__ P,
                                                      const int* __restrict__ idx,
                                                      const float* __restrict__ s5,
                                                      const float* __restrict__ b5,
                                                      float* __restrict__ xo) {
    int t = threadIdx.x, w = t >> 6, lane = t & 63;
    int b = blockIdx.y;
    int n = blockIdx.x * 4 + w;
    int idreg = 0;
    if (lane < 32) idreg = idx[((size_t)(b * NPTS + n)) * KNN + lane];
    float pdd = P[((size_t)(b * NPTS + n)) * 128 + 64 + lane];
    float sc = s5[lane], bi = b5[lane];
    float m = -3.402823466e38f;
    for (int k = 0; k < 32; ++k) {
        int idv = __shfl(idreg, k, 64);
        m = fmaxf(m, P[((size_t)(b * NPTS + idv)) * 128 + lane]);
    }
    xo[((size_t)(b * NPTS + n)) * 64 + lane] = leaky(sc * (m + pdd) + bi);
}

// ---------------- 128x128-tile GEMM for the point-MLP layers ----------------
template <int MODE>
__global__ __launch_bounds__(256) void mlp_gemm(const float* __restrict__ A1,
                                                const float* __restrict__ A2,
                                                const float* __restrict__ A3,
                                                const float* __restrict__ W,
                                                const float* __restrict__ S,
                                                const float* __restrict__ Bi,
                                                const float* __restrict__ gdotv,
                                                float* __restrict__ out,
                                                unsigned* __restrict__ outE) {
    constexpr int KD = (MODE == 2) ? 512 : 192;
    constexpr int ND = (MODE == 0) ? 1024 : (MODE == 1 ? 512 : 256);
    constexpr int WSTR = (MODE == 0) ? 192 : (MODE == 1 ? 1216 : 512);
    constexpr int WOFF = (MODE == 1) ? 1024 : 0;
    __shared__ __align__(16) float As[16][132];
    __shared__ __align__(16) float Bs[16][192];
    int t = threadIdx.x;
    int tx = t & 15, ty = t >> 4;
    int m0 = blockIdx.x * 128, n0 = blockIdx.y * 128;
    float acc[8][8];
    #pragma unroll
    for (int r = 0; r < 8; ++r)
        #pragma unroll
        for (int c = 0; c < 8; ++c) acc[r][c] = 0.f;
    int sm = t >> 1;
    int sk0 = (t & 1) * 8;
    int bc = (sm >> 3) * 12 + (sm & 7);
    for (int k0 = 0; k0 < KD; k0 += 16) {
        const float* Asrc;
        int acol;
        if (MODE == 2) {
            Asrc = A1 + (size_t)(m0 + sm) * 512;
            acol = k0 + sk0;
        } else {
            int sel = k0 >> 6;
            const float* s_ = (sel == 0) ? A1 : (sel == 1 ? A2 : A3);
            Asrc = s_ + (size_t)(m0 + sm) * 64;
            acol = (k0 & 63) + sk0;
        }
        float4 a0 = *(const float4*)&Asrc[acol];
        float4 a1 = *(const float4*)&Asrc[acol + 4];
        float4 b0 = *(const float4*)&W[(size_t)(n0 + sm) * WSTR + WOFF + k0 + sk0];
        float4 b1 = *(const float4*)&W[(size_t)(n0 + sm) * WSTR + WOFF + k0 + sk0 + 4];
        __syncthreads();
        As[sk0 + 0][sm] = a0.x; As[sk0 + 1][sm] = a0.y; As[sk0 + 2][sm] = a0.z; As[sk0 + 3][sm] = a0.w;
        As[sk0 + 4][sm] = a1.x; As[sk0 + 5][sm] = a1.y; As[sk0 + 6][sm] = a1.z; As[sk0 + 7][sm] = a1.w;
        Bs[sk0 + 0][bc] = b0.x; Bs[sk0 + 1][bc] = b0.y; Bs[sk0 + 2][bc] = b0.z; Bs[sk0 + 3][bc] = b0.w;
        Bs[sk0 + 4][bc] = b1.x; Bs[sk0 + 5][bc] = b1.y; Bs[sk0 + 6][bc] = b1.z; Bs[sk0 + 7][bc] = b1.w;
        __syncthreads();
        #pragma unroll
        for (int kk = 0; kk < 16; ++kk) {
            float4 av0 = *(const float4*)&As[kk][ty * 8];
            float4 av1 = *(const float4*)&As[kk][ty * 8 + 4];
            float4 bv0 = *(const float4*)&Bs[kk][tx * 12];
            float4 bv1 = *(const float4*)&Bs[kk][tx * 12 + 4];
            float av[8] = {av0.x, av0.y, av0.z, av0.w, av1.x, av1.y, av1.z, av1.w};
            float bv[8] = {bv0.x, bv0.y, bv0.z, bv0.w, bv1.x, bv1.y, bv1.z, bv1.w};
            #pragma unroll
            for (int r = 0; r < 8; ++r)
                #pragma unroll
                for (int c = 0; c < 8; ++c) acc[r][c] += av[r] * bv[c];
        }
    }
    int b = m0 >> 12;
    if constexpr (MODE == 0) {
        __shared__ float red[16][128];
        float pm[8];
        #pragma unroll
        for (int c = 0; c < 8; ++c) {
            int o = n0 + tx * 8 + c;
            float sc = S[o], bi = Bi[o];
            float gm = -3.402823466e38f;
            #pragma unroll
            for (int r = 0; r < 8; ++r) gm = fmaxf(gm, leaky(sc * acc[r][c] + bi));
            pm[c] = gm;
        }
        __syncthreads();
        #pragma unroll
        for (int c = 0; c < 8; ++c) red[ty][tx * 8 + c] = pm[c];
        __syncthreads();
        if (t < 128) {
            float gm = red[0][t];
            #pragma unroll
            for (int i = 1; i < 16; ++i) gm = fmaxf(gm, red[i][t]);
            atomicMax(&outE[b * 1024 + n0 + t], encf(gm));
        }
    } else {
        #pragma unroll
        for (int r = 0; r < 8; ++r) {
            int m = m0 + ty * 8 + r;
            float4 v0, v1;
            float* vp0 = (float*)&v0;
            float* vp1 = (float*)&v1;
            #pragma unroll
            for (int c = 0; c < 8; ++c) {
                int o = n0 + tx * 8 + c;
                float val = acc[r][c];
                if (MODE == 1) val += gdotv[b * 512 + o];
                float res = leaky(S[o] * val + Bi[o]);
                if (c < 4) vp0[c] = res; else vp1[c - 4] = res;
            }
            *(float4*)&out[(size_t)m * ND + n0 + tx * 8] = v0;
            *(float4*)&out[(size_t)m * ND + n0 + tx * 8 + 4] = v1;
        }
    }
}

// ---------------- gdot[b][o] = sum_c<1024 w7[o][c] * gmax[b][c] ----------------
__global__ __launch_bounds__(256) void gdot_kernel(const unsigned* __restrict__ gmaxE,
                                                   const float* __restrict__ w7,
                                                   float* __restrict__ gdotv) {
    __shared__ float gm[1024];
    int t = threadIdx.x, w = t >> 6, lane = t & 63;
    int b = blockIdx.y;
    int o = blockIdx.x * 4 + w;
    for (int i = t; i < 1024; i += 256) gm[i] = decf(gmaxE[b * 1024 + i]);
    __syncthreads();
    float a = 0.f;
    #pragma unroll
    for (int i = 0; i < 16; ++i) {
        int c = i * 64 + lane;
        a += w7[(size_t)o * 1216 + c] * gm[c];
    }
    #pragma unroll
    for (int d = 32; d; d >>= 1) a += __shfl_xor(a, d, 64);
    if (lane == 0) gdotv[b * 512 + o] = a;
}

// ---------------- final: logits = h256 x w9^T, softmax, transpose out ----------------
__global__ __launch_bounds__(256) void final_kernel(const float* __restrict__ h256,
                                                    const float* __restrict__ w9,
                                                    float* __restrict__ outp) {
    int t = threadIdx.x, w = t >> 6, lane = t & 63;
    int b = blockIdx.y;
    int n = blockIdx.x * 4 + w;
    const float* h = h256 + (size_t)(b * NPTS + n) * 256;
    float a0 = 0.f, a1 = 0.f;
    #pragma unroll
    for (int i = 0; i < 4; ++i) {
        int c = i * 64 + lane;
        float hv = h[c];
        a0 += w9[c] * hv;
        a1 += w9[256 + c] * hv;
    }
    #pragma unroll
    for (int d = 32; d; d >>= 1) {
        a0 += __shfl_xor(a0, d, 64);
        a1 += __shfl_xor(a1, d, 64);
    }
    if (lane == 0) {
        float m = fmaxf(a0, a1);
        float e0 = expf(a0 - m), e1 = expf(a1 - m);
        float s = e0 + e1;
        outp[(size_t)b * 2 * NPTS + n] = e0 / s;
        outp[(size_t)b * 2 * NPTS + NPTS + n] = e1 / s;
    }
}

extern "C" void kernel_launch(void* const* d_in, const int* in_sizes, int n_in,
                              void* d_out, int out_size, void* d_ws, size_t ws_size,
                              hipStream_t stream) {
    (void)in_sizes; (void)n_in; (void)out_size;
    const float* x = (const float*)d_in[0];
    const float* w1 = (const float*)d_in[1];
    const float* w2 = (const float*)d_in[2];
    const float* w3 = (const float*)d_in[3];
    const float* w4 = (const float*)d_in[4];
    const float* w5 = (const float*)d_in[5];
    const float* w6 = (const float*)d_in[6];
    const float* w7 = (const float*)d_in[7];
    const float* w8 = (const float*)d_in[8];
    const float* w9 = (const float*)d_in[9];
    const float* s1 = (const float*)d_in[10]; const float* b1 = (const float*)d_in[11];
    const float* s2 = (const float*)d_in[12]; const float* b2 = (const float*)d_in[13];
    const float* s3 = (const float*)d_in[14]; const float* b3 = (const float*)d_in[15];
    const float* s4 = (const float*)d_in[16]; const float* b4 = (const float*)d_in[17];
    const float* s5 = (const float*)d_in[18]; const float* b5 = (const float*)d_in[19];
    const float* s6 = (const float*)d_in[20]; const float* b6 = (const float*)d_in[21];
    const float* s7 = (const float*)d_in[22]; const float* b7 = (const float*)d_in[23];
    const float* s8 = (const float*)d_in[24]; const float* b8 = (const float*)d_in[25];
    float* out = (float*)d_out;

    // workspace carve-up (floats)
    float* xcl = (float*)d_ws;                       // 131072
    float* x1 = xcl + 131072;                        // 1048576
    float* x2 = x1 + 1048576;                        // 1048576
    float* x3 = x2 + 1048576;                        // 1048576
    float* xxA = x3 + 1048576;                       // 16384
    float* xxB = xxA + 16384;                        // 16384
    float* gdotv = xxB + 16384;                      // 2048
    unsigned* gmaxE = (unsigned*)(gdotv + 2048);     // 4096
    int* idx1 = (int*)(gmaxE + 4096);                // 524288
    int* idx2 = idx1 + 524288;                       // 524288
    int* idx3 = idx2 + 524288;                       // 524288
    float* t512 = (float*)(idx3 + 524288);           // 8388608
    float* h256 = t512 + 8388608;                    // 4194304
    unsigned* Ebuf = (unsigned*)(h256 + 4194304);    // 16777216 per batch slab
    float* Pbuf = t512;                              // alias: P lives in t512

    // 4-batch-wide dist/select if workspace allows 4 E slabs (322.7 MB total);
    // otherwise per-batch loop with one slab (130.7 MB, known-good).
    const unsigned long long ESTR = 16777216ull;
    size_t need4 = (17471488ull + 4ull * ESTR) * 4ull;
    bool batched = ws_size >= need4;

    hipMemsetAsync(gmaxE, 0, 4096 * sizeof(unsigned), stream);

    txcl_kernel<<<512, 256, 0, stream>>>(x, xcl);
    knn1_kernel<<<dim3(1024, 4), 256, 0, stream>>>(x, idx1);
    qpre_kernel<8><<<512, 256, 0, stream>>>(xcl, w1, Pbuf);
    edge_mm_kernel<<<dim3(1024, 4), 256, 0, stream>>>(Pbuf, idx1, s1, b1, w2, s2, b2, x1, xxA);
    if (batched) {
        dist_gemm_kernel<<<dim3(1024, 4), 256, 0, stream>>>(x1, xxA, Ebuf, 0, ESTR);
        knn_select_kernel<<<dim3(1024, 4), 256, 0, stream>>>(Ebuf, idx2, 0, ESTR);
    } else {
        for (int b = 0; b < 4; ++b) {
            dist_gemm_kernel<<<dim3(1024, 1), 256, 0, stream>>>(x1, xxA, Ebuf, b, 0);
            knn_select_kernel<<<dim3(1024, 1), 256, 0, stream>>>(Ebuf, idx2, b, 0);
        }
    }
    qpre_kernel<64><<<512, 256, 0, stream>>>(x1, w3, Pbuf);
    edge_mm_kernel<<<dim3(1024, 4), 256, 0, stream>>>(Pbuf, idx2, s3, b3, w4, s4, b4, x2, xxB);
    if (batched) {
        dist_gemm_kernel<<<dim3(1024, 4), 256, 0, stream>>>(x2, xxB, Ebuf, 0, ESTR);
        knn_select_kernel<<<dim3(1024, 4), 256, 0, stream>>>(Ebuf, idx3, 0, ESTR);
    } else {
        for (int b = 0; b < 4; ++b) {
            dist_gemm_kernel<<<dim3(1024, 1), 256, 0, stream>>>(x2, xxB, Ebuf, b, 0);
            knn_select_kernel<<<dim3(1024, 1), 256, 0, stream>>>(Ebuf, idx3, b, 0);
        }
    }
    qpre_kernel<64><<<512, 256, 0, stream>>>(x2, w5, Pbuf);
    edge3_g_kernel<<<dim3(1024, 4), 256, 0, stream>>>(Pbuf, idx3, s5, b5, x3);
    mlp_gemm<0><<<dim3(128, 8), 256, 0, stream>>>(x1, x2, x3, w6, s6, b6, nullptr, nullptr, gmaxE);
    gdot_kernel<<<dim3(128, 4), 256, 0, stream>>>(gmaxE, w7, gdotv);
    mlp_gemm<1><<<dim3(128, 4), 256, 0, stream>>>(x1, x2, x3, w7, s7, b7, gdotv, t512, nullptr);
    mlp_gemm<2><<<dim3(128, 2), 256, 0, stream>>>(t512, nullptr, nullptr, w8, s8, b8, nullptr, h256, nullptr);
    final_kernel<<<dim3(1024, 4), 256, 0, stream>>>(h256, w9, out);
}

// Round 12
// 1072.892 us; speedup vs baseline: 1.0384x; 1.0384x over previous
//
#include <hip/hip_runtime.h>
#include <cstddef>

#define BATCH 4
#define NPTS 4096
#define KNN 32

__device__ __forceinline__ float leaky(float v) { return v >= 0.f ? v : 0.2f * v; }

// monotone float->uint encoding: larger float => larger uint
__device__ __forceinline__ unsigned encf(float f) {
    unsigned b = __float_as_uint(f);
    return (b & 0x80000000u) ? ~b : (b | 0x80000000u);
}
__device__ __forceinline__ float decf(unsigned e) {
    unsigned b = (e & 0x80000000u) ? (e ^ 0x80000000u) : ~e;
    return __uint_as_float(b);
}
__device__ __forceinline__ unsigned umaxu(unsigned a, unsigned b) { return a > b ? a : b; }

// DPP wave-wide unsigned max; result wave-uniform via readlane 63 -> SGPR.
__device__ __forceinline__ unsigned wave_umax_bcast(unsigned v) {
    int x = (int)v, t;
    t = __builtin_amdgcn_update_dpp(0, x, 0x111, 0xF, 0xF, true); x = (int)umaxu((unsigned)x, (unsigned)t);
    t = __builtin_amdgcn_update_dpp(0, x, 0x112, 0xF, 0xF, true); x = (int)umaxu((unsigned)x, (unsigned)t);
    t = __builtin_amdgcn_update_dpp(0, x, 0x114, 0xF, 0xF, true); x = (int)umaxu((unsigned)x, (unsigned)t);
    t = __builtin_amdgcn_update_dpp(0, x, 0x118, 0xF, 0xF, true); x = (int)umaxu((unsigned)x, (unsigned)t);
    t = __builtin_amdgcn_update_dpp(0, x, 0x142, 0xA, 0xF, true); x = (int)umaxu((unsigned)x, (unsigned)t);
    t = __builtin_amdgcn_update_dpp(0, x, 0x143, 0xC, 0xF, true); x = (int)umaxu((unsigned)x, (unsigned)t);
    return (unsigned)__builtin_amdgcn_readlane(x, 63);
}

// ---------------- one extraction step, v2 (R10-measured-good; v3 regressed — R11) ----------------
// u[64]: lane's values (STATIC indexing only). g[8]: group maxima.
// CM=0: col = 256*(sj>>2) + 4*lane + (sj&3); CM=1: col = sj*64 + lane; CM=2: col = lane*64 + sj.
template <int CM>
__device__ __forceinline__ void extract_step_reg(unsigned* u, unsigned* g, int lane,
                                                 int* __restrict__ outp, int it) {
    unsigned m8 = umaxu(umaxu(umaxu(g[0], g[1]), umaxu(g[2], g[3])),
                        umaxu(umaxu(g[4], g[5]), umaxu(g[6], g[7])));
    unsigned wm = wave_umax_bcast(m8);
    unsigned long long msk = __ballot(m8 == wm);
    int wl = __ffsll(msk) - 1;
    if (lane == wl) {
        int sj = -1;
        #pragma unroll
        for (int G = 0; G < 8; ++G) {
            if (sj < 0 && g[G] == wm) {
                #pragma unroll
                for (int q = 0; q < 8; ++q) {
                    if (sj < 0 && u[G * 8 + q] == wm) { u[G * 8 + q] = 0u; sj = G * 8 + q; }
                }
                unsigned ng = 0u;
                #pragma unroll
                for (int q = 0; q < 8; ++q) ng = umaxu(ng, u[G * 8 + q]);
                g[G] = ng;
            }
        }
        int col;
        if (CM == 0) col = ((sj >> 2) << 8) + (lane << 2) + (sj & 3);
        else if (CM == 1) col = (sj << 6) + lane;
        else col = (lane << 6) + sj;
        outp[it] = col;
    }
}

// ---------------- transpose x (B,8,N) -> xcl (B,N,8) ----------------
__global__ __launch_bounds__(256) void txcl_kernel(const float* __restrict__ x,
                                                   float* __restrict__ xcl) {
    int i = blockIdx.x * 256 + threadIdx.x;
    int n = i & 4095;
    int c = (i >> 12) & 7;
    int b = i >> 15;
    xcl[(size_t)(b * NPTS + n) * 8 + c] = x[i];
}

// ---------------- KNN on 2-d coords: lane owns 64 CONTIGUOUS cols -> float4 loads ----------------
// (R11 fix: was 128 scalar dword loads/lane at wave stride; now 32 float4 loads.)
__global__ __launch_bounds__(256, 4) void knn1_kernel(const float* __restrict__ x,
                                                      int* __restrict__ idxo) {
    int t = threadIdx.x, w = t >> 6, lane = t & 63;
    int b = blockIdx.y;
    int row = blockIdx.x * 4 + w;
    const float* px = x + (size_t)b * 8 * NPTS + 6 * NPTS;
    const float* py = px + NPTS;
    float xr = px[row], yr = py[row];
    const float4* px4 = (const float4*)(px + (lane << 6));
    const float4* py4 = (const float4*)(py + (lane << 6));
    unsigned u[64];
    unsigned g[8];
    #pragma unroll
    for (int i = 0; i < 8; ++i) g[i] = 0u;
    #pragma unroll
    for (int i = 0; i < 16; ++i) {
        float4 xv = px4[i];
        float4 yv = py4[i];
        float xs[4] = {xv.x, xv.y, xv.z, xv.w};
        float ys[4] = {yv.x, yv.y, yv.z, yv.w};
        #pragma unroll
        for (int k = 0; k < 4; ++k) {
            int j = i * 4 + k;
            float v = 2.f * (xr * xs[k] + yr * ys[k]) - (xs[k] * xs[k] + ys[k] * ys[k]);
            unsigned e = encf(v);
            u[j] = e;
            g[j >> 3] = umaxu(g[j >> 3], e);
        }
    }
    int* outp = idxo + ((size_t)(b * NPTS + row) << 5);
    for (int it = 0; it < 32; ++it)
        extract_step_reg<2>(u, g, lane, outp, it);
}

// ---------------- distance GEMM; batch = b0 + blockIdx.y, E slab per blockIdx.y ----------------
__global__ __launch_bounds__(256) void dist_gemm_kernel(const float* __restrict__ feat,
                                                        const float* __restrict__ xx,
                                                        unsigned* __restrict__ E0,
                                                        int b0, unsigned long long estride) {
    int bi = blockIdx.x >> 5, bj = blockIdx.x & 31;
    if (bi > bj) return;
    unsigned* E = E0 + (size_t)blockIdx.y * estride;
    int b = b0 + blockIdx.y;
    __shared__ __align__(16) float As[16][132];
    __shared__ __align__(16) float Bs[16][192];
    int t = threadIdx.x;
    int tx = t & 15, ty = t >> 4;
    const float* fb = feat + (size_t)b * NPTS * 64;
    const float* xb = xx + b * NPTS;
    int m0 = bi * 128, n0 = bj * 128;
    float acc[8][8];
    #pragma unroll
    for (int r = 0; r < 8; ++r)
        #pragma unroll
        for (int c = 0; c < 8; ++c) acc[r][c] = 0.f;
    int sm = t >> 1;
    int sk0 = (t & 1) * 8;
    int bc = (sm >> 3) * 12 + (sm & 7);
    for (int k0 = 0; k0 < 64; k0 += 16) {
        float4 a0 = *(const float4*)&fb[(size_t)(m0 + sm) * 64 + k0 + sk0];
        float4 a1 = *(const float4*)&fb[(size_t)(m0 + sm) * 64 + k0 + sk0 + 4];
        float4 b0v = *(const float4*)&fb[(size_t)(n0 + sm) * 64 + k0 + sk0];
        float4 b1v = *(const float4*)&fb[(size_t)(n0 + sm) * 64 + k0 + sk0 + 4];
        __syncthreads();
        As[sk0 + 0][sm] = a0.x; As[sk0 + 1][sm] = a0.y; As[sk0 + 2][sm] = a0.z; As[sk0 + 3][sm] = a0.w;
        As[sk0 + 4][sm] = a1.x; As[sk0 + 5][sm] = a1.y; As[sk0 + 6][sm] = a1.z; As[sk0 + 7][sm] = a1.w;
        Bs[sk0 + 0][bc] = b0v.x; Bs[sk0 + 1][bc] = b0v.y; Bs[sk0 + 2][bc] = b0v.z; Bs[sk0 + 3][bc] = b0v.w;
        Bs[sk0 + 4][bc] = b1v.x; Bs[sk0 + 5][bc] = b1v.y; Bs[sk0 + 6][bc] = b1v.z; Bs[sk0 + 7][bc] = b1v.w;
        __syncthreads();
        #pragma unroll
        for (int kk = 0; kk < 16; ++kk) {
            float4 av0 = *(const float4*)&As[kk][ty * 8];
            float4 av1 = *(const float4*)&As[kk][ty * 8 + 4];
            float4 bv0 = *(const float4*)&Bs[kk][tx * 12];
            float4 bv1 = *(const float4*)&Bs[kk][tx * 12 + 4];
            float av[8] = {av0.x, av0.y, av0.z, av0.w, av1.x, av1.y, av1.z, av1.w};
            float bv[8] = {bv0.x, bv0.y, bv0.z, bv0.w, bv1.x, bv1.y, bv1.z, bv1.w};
            #pragma unroll
            for (int r = 0; r < 8; ++r)
                #pragma unroll
                for (int c = 0; c < 8; ++c) acc[r][c] += av[r] * bv[c];
        }
    }
    float xxj[8], xxi[8];
    #pragma unroll
    for (int c = 0; c < 8; ++c) xxj[c] = xb[n0 + tx * 8 + c];
    #pragma unroll
    for (int r = 0; r < 8; ++r) xxi[r] = xb[m0 + ty * 8 + r];
    #pragma unroll
    for (int r = 0; r < 8; ++r) {
        uint4 e0, e1;
        e0.x = encf(2.f * acc[r][0] - xxj[0]); e0.y = encf(2.f * acc[r][1] - xxj[1]);
        e0.z = encf(2.f * acc[r][2] - xxj[2]); e0.w = encf(2.f * acc[r][3] - xxj[3]);
        e1.x = encf(2.f * acc[r][4] - xxj[4]); e1.y = encf(2.f * acc[r][5] - xxj[5]);
        e1.z = encf(2.f * acc[r][6] - xxj[6]); e1.w = encf(2.f * acc[r][7] - xxj[7]);
        size_t ro = ((size_t)(m0 + ty * 8 + r) << 12) + n0 + tx * 8;
        *(uint4*)&E[ro] = e0;
        *(uint4*)&E[ro + 4] = e1;
    }
    if (bi != bj) {
        #pragma unroll
        for (int c = 0; c < 8; ++c) {
            uint4 e0, e1;
            e0.x = encf(2.f * acc[0][c] - xxi[0]); e0.y = encf(2.f * acc[1][c] - xxi[1]);
            e0.z = encf(2.f * acc[2][c] - xxi[2]); e0.w = encf(2.f * acc[3][c] - xxi[3]);
            e1.x = encf(2.f * acc[4][c] - xxi[4]); e1.y = encf(2.f * acc[5][c] - xxi[5]);
            e1.z = encf(2.f * acc[6][c] - xxi[6]); e1.w = encf(2.f * acc[7][c] - xxi[7]);
            size_t ro = ((size_t)(n0 + tx * 8 + c) << 12) + m0 + ty * 8;
            *(uint4*)&E[ro] = e0;
            *(uint4*)&E[ro + 4] = e1;
        }
    }
}

// ---------------- select top-32/row from E; batch = b0 + blockIdx.y ----------------
__global__ __launch_bounds__(256, 4) void knn_select_kernel(const unsigned* __restrict__ E0,
                                                            int* __restrict__ idxo,
                                                            int b0, unsigned long long estride) {
    const unsigned* E = E0 + (size_t)blockIdx.y * estride;
    int b = b0 + blockIdx.y;
    int t = threadIdx.x, w = t >> 6, lane = t & 63;
    int row = blockIdx.x * 4 + w;
    const uint4* Er = (const uint4*)(E + ((size_t)row << 12));
    unsigned u[64];
    unsigned g[8];
    #pragma unroll
    for (int i = 0; i < 8; ++i) g[i] = 0u;
    #pragma unroll
    for (int i = 0; i < 16; ++i) {
        uint4 v = Er[i * 64 + lane];
        u[4 * i + 0] = v.x;
        u[4 * i + 1] = v.y;
        u[4 * i + 2] = v.z;
        u[4 * i + 3] = v.w;
        g[i >> 1] = umaxu(g[i >> 1], umaxu(umaxu(v.x, v.y), umaxu(v.z, v.w)));
    }
    int* outp = idxo + ((size_t)(b * NPTS + row) << 5);
    for (int it = 0; it < 32; ++it)
        extract_step_reg<0>(u, g, lane, outp, it);
}

// ---------------- qpre: P[m][o]=Wlo.f_m (o<64), P[m][64+o]=(Whi-Wlo).f_m ----------------
template <int KC>
__global__ __launch_bounds__(256) void qpre_kernel(const float* __restrict__ f,
                                                   const float* __restrict__ W,
                                                   float* __restrict__ P) {
    int t = threadIdx.x, w = t >> 6, lane = t & 63;
    float wlo[KC], wd[KC];
    #pragma unroll
    for (int c = 0; c < KC; c += 4) {
        float4 lo = *(const float4*)&W[lane * 2 * KC + c];
        float4 hi = *(const float4*)&W[lane * 2 * KC + KC + c];
        wlo[c] = lo.x; wlo[c + 1] = lo.y; wlo[c + 2] = lo.z; wlo[c + 3] = lo.w;
        wd[c] = hi.x - lo.x; wd[c + 1] = hi.y - lo.y; wd[c + 2] = hi.z - lo.z; wd[c + 3] = hi.w - lo.w;
    }
    int base = blockIdx.x * 32 + w * 8;
    for (int p = 0; p < 8; ++p) {
        int m = base + p;
        const float* fr = f + (size_t)m * KC;
        float alo = 0.f, ad = 0.f;
        #pragma unroll
        for (int c = 0; c < KC; c += 4) {
            float4 fv = *(const float4*)&fr[c];
            alo += wlo[c] * fv.x + wlo[c + 1] * fv.y + wlo[c + 2] * fv.z + wlo[c + 3] * fv.w;
            ad += wd[c] * fv.x + wd[c + 1] * fv.y + wd[c + 2] * fv.z + wd[c + 3] * fv.w;
        }
        P[(size_t)m * 128 + lane] = alo;
        P[(size_t)m * 128 + 64 + lane] = ad;
    }
}

// ---------------- edge layer as tiled GEMM (R9 structure, unchanged) ----------------
__global__ __launch_bounds__(256) void edge_mm_kernel(const float* __restrict__ P,
                                                      const int* __restrict__ idx,
                                                      const float* __restrict__ sA,
                                                      const float* __restrict__ bA,
                                                      const float* __restrict__ W2,
                                                      const float* __restrict__ sB,
                                                      const float* __restrict__ bB,
                                                      float* __restrict__ xo,
                                                      float* __restrict__ xxo) {
    __shared__ __align__(16) float h1T[64][132];
    __shared__ __align__(16) float Bs[64][68];
    __shared__ __align__(16) float pdd_s[4][64];
    __shared__ float scA_s[64], biA_s[64];
    __shared__ int ids[128];
    int t = threadIdx.x;
    int b = blockIdx.y;
    int n0 = blockIdx.x * 4;
    if (t < 128) ids[t] = idx[((size_t)(b * NPTS + n0 + (t >> 5))) * KNN + (t & 31)];
    else if (t < 192) scA_s[t - 128] = sA[t - 128];
    else biA_s[t - 192] = bA[t - 192];
    pdd_s[t >> 6][t & 63] = P[((size_t)(b * NPTS + n0 + (t >> 6))) * 128 + 64 + (t & 63)];
    __syncthreads();
    {
        int o = t & 63, kk0 = (t >> 6) * 16;
        #pragma unroll
        for (int j = 0; j < 16; j += 4) {
            float4 v = *(const float4*)&W2[o * 64 + kk0 + j];
            Bs[kk0 + j + 0][o] = v.x;
            Bs[kk0 + j + 1][o] = v.y;
            Bs[kk0 + j + 2][o] = v.z;
            Bs[kk0 + j + 3][o] = v.w;
        }
    }
    #pragma unroll
    for (int p = 0; p < 2; ++p) {
        int row = p * 64 + (t >> 2);
        int w = row >> 5;
        int id = ids[row];
        int q = t & 3;
        const float* src = &P[((size_t)(b * NPTS + id)) * 128 + q * 16];
        #pragma unroll
        for (int j = 0; j < 4; ++j) {
            int c = q * 16 + j * 4;
            float4 v = *(const float4*)&src[j * 4];
            float4 sa = *(const float4*)&scA_s[c];
            float4 ba = *(const float4*)&biA_s[c];
            float4 pd = *(const float4*)&pdd_s[w][c];
            h1T[c + 0][row] = leaky(sa.x * (v.x + pd.x) + ba.x);
            h1T[c + 1][row] = leaky(sa.y * (v.y + pd.y) + ba.y);
            h1T[c + 2][row] = leaky(sa.z * (v.z + pd.z) + ba.z);
            h1T[c + 3][row] = leaky(sa.w * (v.w + pd.w) + ba.w);
        }
    }
    __syncthreads();
    int tx = t & 15, ty = t >> 4;
    float acc[8][4];
    #pragma unroll
    for (int r = 0; r < 8; ++r)
        #pragma unroll
        for (int c = 0; c < 4; ++c) acc[r][c] = 0.f;
    #pragma unroll 4
    for (int kk = 0; kk < 64; ++kk) {
        float4 a0 = *(const float4*)&h1T[kk][ty * 8];
        float4 a1 = *(const float4*)&h1T[kk][ty * 8 + 4];
        float4 bb = *(const float4*)&Bs[kk][tx * 4];
        float av[8] = {a0.x, a0.y, a0.z, a0.w, a1.x, a1.y, a1.z, a1.w};
        #pragma unroll
        for (int r = 0; r < 8; ++r) {
            acc[r][0] += av[r] * bb.x;
            acc[r][1] += av[r] * bb.y;
            acc[r][2] += av[r] * bb.z;
            acc[r][3] += av[r] * bb.w;
        }
    }
    float rm[4];
    #pragma unroll
    for (int c = 0; c < 4; ++c) {
        float m = acc[0][c];
        #pragma unroll
        for (int r = 1; r < 8; ++r) m = fmaxf(m, acc[r][c]);
        rm[c] = m;
    }
    __syncthreads();
    float (*red)[68] = Bs;
    #pragma unroll
    for (int c = 0; c < 4; ++c) red[ty][tx * 4 + c] = rm[c];
    __syncthreads();
    int w = t >> 6, lane = t & 63;
    float m = fmaxf(fmaxf(red[4 * w + 0][lane], red[4 * w + 1][lane]),
                    fmaxf(red[4 * w + 2][lane], red[4 * w + 3][lane]));
    float outv = leaky(sB[lane] * m + bB[lane]);
    xo[((size_t)(b * NPTS + n0 + w)) * 64 + lane] = outv;
    if (xxo != nullptr) {
        float sq = outv * outv;
        #pragma unroll
        for (int d = 32; d; d >>= 1) sq += __shfl_xor(sq, d, 64);
        if (lane == 0) xxo[b * NPTS + n0 + w] = sq;
    }
}

// ---------------- edge layer 3: gather + max, activation hoisted (s5>0) ----------------
__global__ __launch_bounds__(256) void edge3_g_kernel(const float* __restrict__ P,
                                                      const int* __restrict__ idx,
                                                      const float* __restrict__ s5,
                                                      const float* __restrict__ b5,
                                                      float* __restrict__ xo) {
    int t = threadIdx.x, w = t >> 6, lane = t & 63;
    int b = blockIdx.y;
    int n = blockIdx.x * 4 + w;
    int idreg = 0;
    if (lane < 32) idreg = idx[((size_t)(b * NPTS + n)) * KNN + lane];
    float pdd = P[((size_t)(b * NPTS + n)) * 128 + 64 + lane];
    float sc = s5[lane], bi = b5[lane];
    float m = -3.402823466e38f;
    for (int k = 0; k < 32; ++k) {
        int idv = __shfl(idreg, k, 64);
        m = fmaxf(m, P[((size_t)(b * NPTS + idv)) * 128 + lane]);
    }
    xo[((size_t)(b * NPTS + n)) * 64 + lane] = leaky(sc * (m + pdd) + bi);
}

// ---------------- 128x128-tile GEMM for the point-MLP layers ----------------
template <int MODE>
__global__ __launch_bounds__(256) void mlp_gemm(const float* __restrict__ A1,
                                                const float* __restrict__ A2,
                                                const float* __restrict__ A3,
                                                const float* __restrict__ W,
                                                const float* __restrict__ S,
                                                const float* __restrict__ Bi,
                                                const float* __restrict__ gdotv,
                                                float* __restrict__ out,
                                                unsigned* __restrict__ outE) {
    constexpr int KD = (MODE == 2) ? 512 : 192;
    constexpr int ND = (MODE == 0) ? 1024 : (MODE == 1 ? 512 : 256);
    constexpr int WSTR = (MODE == 0) ? 192 : (MODE == 1 ? 1216 : 512);
    constexpr int WOFF = (MODE == 1) ? 1024 : 0;
    __shared__ __align__(16) float As[16][132];
    __shared__ __align__(16) float Bs[16][192];
    int t = threadIdx.x;
    int tx = t & 15, ty = t >> 4;
    int m0 = blockIdx.x * 128, n0 = blockIdx.y * 128;
    float acc[8][8];
    #pragma unroll
    for (int r = 0; r < 8; ++r)
        #pragma unroll
        for (int c = 0; c < 8; ++c) acc[r][c] = 0.f;
    int sm = t >> 1;
    int sk0 = (t & 1) * 8;
    int bc = (sm >> 3) * 12 + (sm & 7);
    for (int k0 = 0; k0 < KD; k0 += 16) {
        const float* Asrc;
        int acol;
        if (MODE == 2) {
            Asrc = A1 + (size_t)(m0 + sm) * 512;
            acol = k0 + sk0;
        } else {
            int sel = k0 >> 6;
            const float* s_ = (sel == 0) ? A1 : (sel == 1 ? A2 : A3);
            Asrc = s_ + (size_t)(m0 + sm) * 64;
            acol = (k0 & 63) + sk0;
        }
        float4 a0 = *(const float4*)&Asrc[acol];
        float4 a1 = *(const float4*)&Asrc[acol + 4];
        float4 b0 = *(const float4*)&W[(size_t)(n0 + sm) * WSTR + WOFF + k0 + sk0];
        float4 b1 = *(const float4*)&W[(size_t)(n0 + sm) * WSTR + WOFF + k0 + sk0 + 4];
        __syncthreads();
        As[sk0 + 0][sm] = a0.x; As[sk0 + 1][sm] = a0.y; As[sk0 + 2][sm] = a0.z; As[sk0 + 3][sm] = a0.w;
        As[sk0 + 4][sm] = a1.x; As[sk0 + 5][sm] = a1.y; As[sk0 + 6][sm] = a1.z; As[sk0 + 7][sm] = a1.w;
        Bs[sk0 + 0][bc] = b0.x; Bs[sk0 + 1][bc] = b0.y; Bs[sk0 + 2][bc] = b0.z; Bs[sk0 + 3][bc] = b0.w;
        Bs[sk0 + 4][bc] = b1.x; Bs[sk0 + 5][bc] = b1.y; Bs[sk0 + 6][bc] = b1.z; Bs[sk0 + 7][bc] = b1.w;
        __syncthreads();
        #pragma unroll
        for (int kk = 0; kk < 16; ++kk) {
            float4 av0 = *(const float4*)&As[kk][ty * 8];
            float4 av1 = *(const float4*)&As[kk][ty * 8 + 4];
            float4 bv0 = *(const float4*)&Bs[kk][tx * 12];
            float4 bv1 = *(const float4*)&Bs[kk][tx * 12 + 4];
            float av[8] = {av0.x, av0.y, av0.z, av0.w, av1.x, av1.y, av1.z, av1.w};
            float bv[8] = {bv0.x, bv0.y, bv0.z, bv0.w, bv1.x, bv1.y, bv1.z, bv1.w};
            #pragma unroll
            for (int r = 0; r < 8; ++r)
                #pragma unroll
                for (int c = 0; c < 8; ++c) acc[r][c] += av[r] * bv[c];
        }
    }
    int b = m0 >> 12;
    if constexpr (MODE == 0) {
        __shared__ float red[16][128];
        float pm[8];
        #pragma unroll
        for (int c = 0; c < 8; ++c) {
            int o = n0 + tx * 8 + c;
            float sc = S[o], bi = Bi[o];
            float gm = -3.402823466e38f;
            #pragma unroll
            for (int r = 0; r < 8; ++r) gm = fmaxf(gm, leaky(sc * acc[r][c] + bi));
            pm[c] = gm;
        }
        __syncthreads();
        #pragma unroll
        for (int c = 0; c < 8; ++c) red[ty][tx * 8 + c] = pm[c];
        __syncthreads();
        if (t < 128) {
            float gm = red[0][t];
            #pragma unroll
            for (int i = 1; i < 16; ++i) gm = fmaxf(gm, red[i][t]);
            atomicMax(&outE[b * 1024 + n0 + t], encf(gm));
        }
    } else {
        #pragma unroll
        for (int r = 0; r < 8; ++r) {
            int m = m0 + ty * 8 + r;
            float4 v0, v1;
            float* vp0 = (float*)&v0;
            float* vp1 = (float*)&v1;
            #pragma unroll
            for (int c = 0; c < 8; ++c) {
                int o = n0 + tx * 8 + c;
                float val = acc[r][c];
                if (MODE == 1) val += gdotv[b * 512 + o];
                float res = leaky(S[o] * val + Bi[o]);
                if (c < 4) vp0[c] = res; else vp1[c - 4] = res;
            }
            *(float4*)&out[(size_t)m * ND + n0 + tx * 8] = v0;
            *(float4*)&out[(size_t)m * ND + n0 + tx * 8 + 4] = v1;
        }
    }
}

// ---------------- gdot[b][o] = sum_c<1024 w7[o][c] * gmax[b][c] ----------------
__global__ __launch_bounds__(256) void gdot_kernel(const unsigned* __restrict__ gmaxE,
                                                   const float* __restrict__ w7,
                                                   float* __restrict__ gdotv) {
    __shared__ float gm[1024];
    int t = threadIdx.x, w = t >> 6, lane = t & 63;
    int b = blockIdx.y;
    int o = blockIdx.x * 4 + w;
    for (int i = t; i < 1024; i += 256) gm[i] = decf(gmaxE[b * 1024 + i]);
    __syncthreads();
    float a = 0.f;
    #pragma unroll
    for (int i = 0; i < 16; ++i) {
        int c = i * 64 + lane;
        a += w7[(size_t)o * 1216 + c] * gm[c];
    }
    #pragma unroll
    for (int d = 32; d; d >>= 1) a += __shfl_xor(a, d, 64);
    if (lane == 0) gdotv[b * 512 + o] = a;
}

// ---------------- final: logits = h256 x w9^T, softmax, transpose out ----------------
__global__ __launch_bounds__(256) void final_kernel(const float* __restrict__ h256,
                                                    const float* __restrict__ w9,
                                                    float* __restrict__ outp) {
    int t = threadIdx.x, w = t >> 6, lane = t & 63;
    int b = blockIdx.y;
    int n = blockIdx.x * 4 + w;
    const float* h = h256 + (size_t)(b * NPTS + n) * 256;
    float a0 = 0.f, a1 = 0.f;
    #pragma unroll
    for (int i = 0; i < 4; ++i) {
        int c = i * 64 + lane;
        float hv = h[c];
        a0 += w9[c] * hv;
        a1 += w9[256 + c] * hv;
    }
    #pragma unroll
    for (int d = 32; d; d >>= 1) {
        a0 += __shfl_xor(a0, d, 64);
        a1 += __shfl_xor(a1, d, 64);
    }
    if (lane == 0) {
        float m = fmaxf(a0, a1);
        float e0 = expf(a0 - m), e1 = expf(a1 - m);
        float s = e0 + e1;
        outp[(size_t)b * 2 * NPTS + n] = e0 / s;
        outp[(size_t)b * 2 * NPTS + NPTS + n] = e1 / s;
    }
}

extern "C" void kernel_launch(void* const* d_in, const int* in_sizes, int n_in,
                              void* d_out, int out_size, void* d_ws, size_t ws_size,
                              hipStream_t stream) {
    (void)in_sizes; (void)n_in; (void)out_size;
    const float* x = (const float*)d_in[0];
    const float* w1 = (const float*)d_in[1];
    const float* w2 = (const float*)d_in[2];
    const float* w3 = (const float*)d_in[3];
    const float* w4 = (const float*)d_in[4];
    const float* w5 = (const float*)d_in[5];
    const float* w6 = (const float*)d_in[6];
    const float* w7 = (const float*)d_in[7];
    const float* w8 = (const float*)d_in[8];
    const float* w9 = (const float*)d_in[9];
    const float* s1 = (const float*)d_in[10]; const float* b1 = (const float*)d_in[11];
    const float* s2 = (const float*)d_in[12]; const float* b2 = (const float*)d_in[13];
    const float* s3 = (const float*)d_in[14]; const float* b3 = (const float*)d_in[15];
    const float* s4 = (const float*)d_in[16]; const float* b4 = (const float*)d_in[17];
    const float* s5 = (const float*)d_in[18]; const float* b5 = (const float*)d_in[19];
    const float* s6 = (const float*)d_in[20]; const float* b6 = (const float*)d_in[21];
    const float* s7 = (const float*)d_in[22]; const float* b7 = (const float*)d_in[23];
    const float* s8 = (const float*)d_in[24]; const float* b8 = (const float*)d_in[25];
    float* out = (float*)d_out;

    // workspace carve-up (floats)
    float* xcl = (float*)d_ws;                       // 131072
    float* x1 = xcl + 131072;                        // 1048576
    float* x2 = x1 + 1048576;                        // 1048576
    float* x3 = x2 + 1048576;                        // 1048576
    float* xxA = x3 + 1048576;                       // 16384
    float* xxB = xxA + 16384;                        // 16384
    float* gdotv = xxB + 16384;                      // 2048
    unsigned* gmaxE = (unsigned*)(gdotv + 2048);     // 4096
    int* idx1 = (int*)(gmaxE + 4096);                // 524288
    int* idx2 = idx1 + 524288;                       // 524288
    int* idx3 = idx2 + 524288;                       // 524288
    float* t512 = (float*)(idx3 + 524288);           // 8388608
    float* h256 = t512 + 8388608;                    // 4194304
    unsigned* Ebuf = (unsigned*)(h256 + 4194304);    // 16777216 per batch slab
    float* Pbuf = t512;                              // alias: P lives in t512

    // 4-batch-wide dist/select if workspace allows 4 E slabs; else per-batch loop.
    const unsigned long long ESTR = 16777216ull;
    size_t need4 = (17471488ull + 4ull * ESTR) * 4ull;
    bool batched = ws_size >= need4;

    hipMemsetAsync(gmaxE, 0, 4096 * sizeof(unsigned), stream);

    txcl_kernel<<<512, 256, 0, stream>>>(x, xcl);
    knn1_kernel<<<dim3(1024, 4), 256, 0, stream>>>(x, idx1);
    qpre_kernel<8><<<512, 256, 0, stream>>>(xcl, w1, Pbuf);
    edge_mm_kernel<<<dim3(1024, 4), 256, 0, stream>>>(Pbuf, idx1, s1, b1, w2, s2, b2, x1, xxA);
    if (batched) {
        dist_gemm_kernel<<<dim3(1024, 4), 256, 0, stream>>>(x1, xxA, Ebuf, 0, ESTR);
        knn_select_kernel<<<dim3(1024, 4), 256, 0, stream>>>(Ebuf, idx2, 0, ESTR);
    } else {
        for (int b = 0; b < 4; ++b) {
            dist_gemm_kernel<<<dim3(1024, 1), 256, 0, stream>>>(x1, xxA, Ebuf, b, 0);
            knn_select_kernel<<<dim3(1024, 1), 256, 0, stream>>>(Ebuf, idx2, b, 0);
        }
    }
    qpre_kernel<64><<<512, 256, 0, stream>>>(x1, w3, Pbuf);
    edge_mm_kernel<<<dim3(1024, 4), 256, 0, stream>>>(Pbuf, idx2, s3, b3, w4, s4, b4, x2, xxB);
    if (batched) {
        dist_gemm_kernel<<<dim3(1024, 4), 256, 0, stream>>>(x2, xxB, Ebuf, 0, ESTR);
        knn_select_kernel<<<dim3(1024, 4), 256, 0, stream>>>(Ebuf, idx3, 0, ESTR);
    } else {
        for (int b = 0; b < 4; ++b) {
            dist_gemm_kernel<<<dim3(1024, 1), 256, 0, stream>>>(x2, xxB, Ebuf, b, 0);
            knn_select_kernel<<<dim3(1024, 1), 256, 0, stream>>>(Ebuf, idx3, b, 0);
        }
    }
    qpre_kernel<64><<<512, 256, 0, stream>>>(x2, w5, Pbuf);
    edge3_g_kernel<<<dim3(1024, 4), 256, 0, stream>>>(Pbuf, idx3, s5, b5, x3);
    mlp_gemm<0><<<dim3(128, 8), 256, 0, stream>>>(x1, x2, x3, w6, s6, b6, nullptr, nullptr, gmaxE);
    gdot_kernel<<<dim3(128, 4), 256, 0, stream>>>(gmaxE, w7, gdotv);
    mlp_gemm<1><<<dim3(128, 4), 256, 0, stream>>>(x1, x2, x3, w7, s7, b7, gdotv, t512, nullptr);
    mlp_gemm<2><<<dim3(128, 2), 256, 0, stream>>>(t512, nullptr, nullptr, w8, s8, b8, nullptr, h256, nullptr);
    final_kernel<<<dim3(1024, 4), 256, 0, stream>>>(h256, w9, out);
}

// Round 13
// 1063.746 us; speedup vs baseline: 1.0473x; 1.0086x over previous
//
#include <hip/hip_runtime.h>
#include <cstddef>

#define BATCH 4
#define NPTS 4096
#define KNN 32

__device__ __forceinline__ float leaky(float v) { return v >= 0.f ? v : 0.2f * v; }

// monotone float->uint encoding: larger float => larger uint
__device__ __forceinline__ unsigned encf(float f) {
    unsigned b = __float_as_uint(f);
    return (b & 0x80000000u) ? ~b : (b | 0x80000000u);
}
__device__ __forceinline__ float decf(unsigned e) {
    unsigned b = (e & 0x80000000u) ? (e ^ 0x80000000u) : ~e;
    return __uint_as_float(b);
}
__device__ __forceinline__ unsigned umaxu(unsigned a, unsigned b) { return a > b ? a : b; }

// DPP wave-wide unsigned max; result wave-uniform via readlane 63 -> SGPR.
__device__ __forceinline__ unsigned wave_umax_bcast(unsigned v) {
    int x = (int)v, t;
    t = __builtin_amdgcn_update_dpp(0, x, 0x111, 0xF, 0xF, true); x = (int)umaxu((unsigned)x, (unsigned)t);
    t = __builtin_amdgcn_update_dpp(0, x, 0x112, 0xF, 0xF, true); x = (int)umaxu((unsigned)x, (unsigned)t);
    t = __builtin_amdgcn_update_dpp(0, x, 0x114, 0xF, 0xF, true); x = (int)umaxu((unsigned)x, (unsigned)t);
    t = __builtin_amdgcn_update_dpp(0, x, 0x118, 0xF, 0xF, true); x = (int)umaxu((unsigned)x, (unsigned)t);
    t = __builtin_amdgcn_update_dpp(0, x, 0x142, 0xA, 0xF, true); x = (int)umaxu((unsigned)x, (unsigned)t);
    t = __builtin_amdgcn_update_dpp(0, x, 0x143, 0xC, 0xF, true); x = (int)umaxu((unsigned)x, (unsigned)t);
    return (unsigned)__builtin_amdgcn_readlane(x, 63);
}

// ---------------- one extraction step, v2 (R10-measured-good) ----------------
// u[64]: lane's values (STATIC indexing only). g[8]: group maxima.
// CM=0: col = 256*(sj>>2) + 4*lane + (sj&3); CM=1: col = sj*64 + lane.
template <int CM>
__device__ __forceinline__ void extract_step_reg(unsigned* u, unsigned* g, int lane,
                                                 int* __restrict__ outp, int it) {
    unsigned m8 = umaxu(umaxu(umaxu(g[0], g[1]), umaxu(g[2], g[3])),
                        umaxu(umaxu(g[4], g[5]), umaxu(g[6], g[7])));
    unsigned wm = wave_umax_bcast(m8);
    unsigned long long msk = __ballot(m8 == wm);
    int wl = __ffsll(msk) - 1;
    if (lane == wl) {
        int sj = -1;
        #pragma unroll
        for (int G = 0; G < 8; ++G) {
            if (sj < 0 && g[G] == wm) {
                #pragma unroll
                for (int q = 0; q < 8; ++q) {
                    if (sj < 0 && u[G * 8 + q] == wm) { u[G * 8 + q] = 0u; sj = G * 8 + q; }
                }
                unsigned ng = 0u;
                #pragma unroll
                for (int q = 0; q < 8; ++q) ng = umaxu(ng, u[G * 8 + q]);
                g[G] = ng;
            }
        }
        int col;
        if (CM == 0) col = ((sj >> 2) << 8) + (lane << 2) + (sj & 3);
        else col = (sj << 6) + lane;
        outp[it] = col;
    }
}

// ---------------- transpose x (B,8,N) -> xcl (B,N,8) ----------------
__global__ __launch_bounds__(256) void txcl_kernel(const float* __restrict__ x,
                                                   float* __restrict__ xcl) {
    int i = blockIdx.x * 256 + threadIdx.x;
    int n = i & 4095;
    int c = (i >> 12) & 7;
    int b = i >> 15;
    xcl[(size_t)(b * NPTS + n) * 8 + c] = x[i];
}

// ---------------- KNN on 2-d coords: R10-exact (scalar loads, CM=1; 89us measured).
// R12's float4-contiguous remap regressed (VGPR 40->48, occ 55->48): kernel is
// latency-bound on the extraction chain, not VMEM-issue-bound.
__global__ __launch_bounds__(256, 4) void knn1_kernel(const float* __restrict__ x,
                                                      int* __restrict__ idxo) {
    int t = threadIdx.x, w = t >> 6, lane = t & 63;
    int b = blockIdx.y;
    int row = blockIdx.x * 4 + w;
    const float* px = x + (size_t)b * 8 * NPTS + 6 * NPTS;
    const float* py = px + NPTS;
    float xr = px[row], yr = py[row];
    unsigned u[64];
    unsigned g[8];
    #pragma unroll
    for (int i = 0; i < 8; ++i) g[i] = 0u;
    #pragma unroll
    for (int j = 0; j < 64; ++j) {
        int col = (j << 6) + lane;
        float xm = px[col], ym = py[col];
        float v = 2.f * (xr * xm + yr * ym) - (xm * xm + ym * ym);
        unsigned e = encf(v);
        u[j] = e;
        g[j >> 3] = umaxu(g[j >> 3], e);
    }
    int* outp = idxo + ((size_t)(b * NPTS + row) << 5);
    for (int it = 0; it < 32; ++it)
        extract_step_reg<1>(u, g, lane, outp, it);
}

// ---------------- distance GEMM; batch = b0 + blockIdx.y, E slab per blockIdx.y ----------------
__global__ __launch_bounds__(256) void dist_gemm_kernel(const float* __restrict__ feat,
                                                        const float* __restrict__ xx,
                                                        unsigned* __restrict__ E0,
                                                        int b0, unsigned long long estride) {
    int bi = blockIdx.x >> 5, bj = blockIdx.x & 31;
    if (bi > bj) return;
    unsigned* E = E0 + (size_t)blockIdx.y * estride;
    int b = b0 + blockIdx.y;
    __shared__ __align__(16) float As[16][132];
    __shared__ __align__(16) float Bs[16][192];
    int t = threadIdx.x;
    int tx = t & 15, ty = t >> 4;
    const float* fb = feat + (size_t)b * NPTS * 64;
    const float* xb = xx + b * NPTS;
    int m0 = bi * 128, n0 = bj * 128;
    float acc[8][8];
    #pragma unroll
    for (int r = 0; r < 8; ++r)
        #pragma unroll
        for (int c = 0; c < 8; ++c) acc[r][c] = 0.f;
    int sm = t >> 1;
    int sk0 = (t & 1) * 8;
    int bc = (sm >> 3) * 12 + (sm & 7);
    for (int k0 = 0; k0 < 64; k0 += 16) {
        float4 a0 = *(const float4*)&fb[(size_t)(m0 + sm) * 64 + k0 + sk0];
        float4 a1 = *(const float4*)&fb[(size_t)(m0 + sm) * 64 + k0 + sk0 + 4];
        float4 b0v = *(const float4*)&fb[(size_t)(n0 + sm) * 64 + k0 + sk0];
        float4 b1v = *(const float4*)&fb[(size_t)(n0 + sm) * 64 + k0 + sk0 + 4];
        __syncthreads();
        As[sk0 + 0][sm] = a0.x; As[sk0 + 1][sm] = a0.y; As[sk0 + 2][sm] = a0.z; As[sk0 + 3][sm] = a0.w;
        As[sk0 + 4][sm] = a1.x; As[sk0 + 5][sm] = a1.y; As[sk0 + 6][sm] = a1.z; As[sk0 + 7][sm] = a1.w;
        Bs[sk0 + 0][bc] = b0v.x; Bs[sk0 + 1][bc] = b0v.y; Bs[sk0 + 2][bc] = b0v.z; Bs[sk0 + 3][bc] = b0v.w;
        Bs[sk0 + 4][bc] = b1v.x; Bs[sk0 + 5][bc] = b1v.y; Bs[sk0 + 6][bc] = b1v.z; Bs[sk0 + 7][bc] = b1v.w;
        __syncthreads();
        #pragma unroll
        for (int kk = 0; kk < 16; ++kk) {
            float4 av0 = *(const float4*)&As[kk][ty * 8];
            float4 av1 = *(const float4*)&As[kk][ty * 8 + 4];
            float4 bv0 = *(const float4*)&Bs[kk][tx * 12];
            float4 bv1 = *(const float4*)&Bs[kk][tx * 12 + 4];
            float av[8] = {av0.x, av0.y, av0.z, av0.w, av1.x, av1.y, av1.z, av1.w};
            float bv[8] = {bv0.x, bv0.y, bv0.z, bv0.w, bv1.x, bv1.y, bv1.z, bv1.w};
            #pragma unroll
            for (int r = 0; r < 8; ++r)
                #pragma unroll
                for (int c = 0; c < 8; ++c) acc[r][c] += av[r] * bv[c];
        }
    }
    float xxj[8], xxi[8];
    #pragma unroll
    for (int c = 0; c < 8; ++c) xxj[c] = xb[n0 + tx * 8 + c];
    #pragma unroll
    for (int r = 0; r < 8; ++r) xxi[r] = xb[m0 + ty * 8 + r];
    #pragma unroll
    for (int r = 0; r < 8; ++r) {
        uint4 e0, e1;
        e0.x = encf(2.f * acc[r][0] - xxj[0]); e0.y = encf(2.f * acc[r][1] - xxj[1]);
        e0.z = encf(2.f * acc[r][2] - xxj[2]); e0.w = encf(2.f * acc[r][3] - xxj[3]);
        e1.x = encf(2.f * acc[r][4] - xxj[4]); e1.y = encf(2.f * acc[r][5] - xxj[5]);
        e1.z = encf(2.f * acc[r][6] - xxj[6]); e1.w = encf(2.f * acc[r][7] - xxj[7]);
        size_t ro = ((size_t)(m0 + ty * 8 + r) << 12) + n0 + tx * 8;
        *(uint4*)&E[ro] = e0;
        *(uint4*)&E[ro + 4] = e1;
    }
    if (bi != bj) {
        #pragma unroll
        for (int c = 0; c < 8; ++c) {
            uint4 e0, e1;
            e0.x = encf(2.f * acc[0][c] - xxi[0]); e0.y = encf(2.f * acc[1][c] - xxi[1]);
            e0.z = encf(2.f * acc[2][c] - xxi[2]); e0.w = encf(2.f * acc[3][c] - xxi[3]);
            e1.x = encf(2.f * acc[4][c] - xxi[4]); e1.y = encf(2.f * acc[5][c] - xxi[5]);
            e1.z = encf(2.f * acc[6][c] - xxi[6]); e1.w = encf(2.f * acc[7][c] - xxi[7]);
            size_t ro = ((size_t)(n0 + tx * 8 + c) << 12) + m0 + ty * 8;
            *(uint4*)&E[ro] = e0;
            *(uint4*)&E[ro + 4] = e1;
        }
    }
}

// ---------------- select top-32/row from E; batch = b0 + blockIdx.y ----------------
__global__ __launch_bounds__(256, 4) void knn_select_kernel(const unsigned* __restrict__ E0,
                                                            int* __restrict__ idxo,
                                                            int b0, unsigned long long estride) {
    const unsigned* E = E0 + (size_t)blockIdx.y * estride;
    int b = b0 + blockIdx.y;
    int t = threadIdx.x, w = t >> 6, lane = t & 63;
    int row = blockIdx.x * 4 + w;
    const uint4* Er = (const uint4*)(E + ((size_t)row << 12));
    unsigned u[64];
    unsigned g[8];
    #pragma unroll
    for (int i = 0; i < 8; ++i) g[i] = 0u;
    #pragma unroll
    for (int i = 0; i < 16; ++i) {
        uint4 v = Er[i * 64 + lane];
        u[4 * i + 0] = v.x;
        u[4 * i + 1] = v.y;
        u[4 * i + 2] = v.z;
        u[4 * i + 3] = v.w;
        g[i >> 1] = umaxu(g[i >> 1], umaxu(umaxu(v.x, v.y), umaxu(v.z, v.w)));
    }
    int* outp = idxo + ((size_t)(b * NPTS + row) << 5);
    for (int it = 0; it < 32; ++it)
        extract_step_reg<0>(u, g, lane, outp, it);
}

// ---------------- qpre: P[m][o]=Wlo.f_m (o<64), P[m][64+o]=(Whi-Wlo).f_m ----------------
template <int KC>
__global__ __launch_bounds__(256) void qpre_kernel(const float* __restrict__ f,
                                                   const float* __restrict__ W,
                                                   float* __restrict__ P) {
    int t = threadIdx.x, w = t >> 6, lane = t & 63;
    float wlo[KC], wd[KC];
    #pragma unroll
    for (int c = 0; c < KC; c += 4) {
        float4 lo = *(const float4*)&W[lane * 2 * KC + c];
        float4 hi = *(const float4*)&W[lane * 2 * KC + KC + c];
        wlo[c] = lo.x; wlo[c + 1] = lo.y; wlo[c + 2] = lo.z; wlo[c + 3] = lo.w;
        wd[c] = hi.x - lo.x; wd[c + 1] = hi.y - lo.y; wd[c + 2] = hi.z - lo.z; wd[c + 3] = hi.w - lo.w;
    }
    int base = blockIdx.x * 32 + w * 8;
    for (int p = 0; p < 8; ++p) {
        int m = base + p;
        const float* fr = f + (size_t)m * KC;
        float alo = 0.f, ad = 0.f;
        #pragma unroll
        for (int c = 0; c < KC; c += 4) {
            float4 fv = *(const float4*)&fr[c];
            alo += wlo[c] * fv.x + wlo[c + 1] * fv.y + wlo[c + 2] * fv.z + wlo[c + 3] * fv.w;
            ad += wd[c] * fv.x + wd[c + 1] * fv.y + wd[c + 2] * fv.z + wd[c + 3] * fv.w;
        }
        P[(size_t)m * 128 + lane] = alo;
        P[(size_t)m * 128 + 64 + lane] = ad;
    }
}

// ---------------- edge layer as tiled GEMM (R9 structure) ----------------
__global__ __launch_bounds__(256) void edge_mm_kernel(const float* __restrict__ P,
                                                      const int* __restrict__ idx,
                                                      const float* __restrict__ sA,
                                                      const float* __restrict__ bA,
                                                      const float* __restrict__ W2,
                                                      const float* __restrict__ sB,
                                                      const float* __restrict__ bB,
                                                      float* __restrict__ xo,
                                                      float* __restrict__ xxo) {
    __shared__ __align__(16) float h1T[64][132];
    __shared__ __align__(16) float Bs[64][68];
    __shared__ __align__(16) float pdd_s[4][64];
    __shared__ float scA_s[64], biA_s[64];
    __shared__ int ids[128];
    int t = threadIdx.x;
    int b = blockIdx.y;
    int n0 = blockIdx.x * 4;
    if (t < 128) ids[t] = idx[((size_t)(b * NPTS + n0 + (t >> 5))) * KNN + (t & 31)];
    else if (t < 192) scA_s[t - 128] = sA[t - 128];
    else biA_s[t - 192] = bA[t - 192];
    pdd_s[t >> 6][t & 63] = P[((size_t)(b * NPTS + n0 + (t >> 6))) * 128 + 64 + (t & 63)];
    __syncthreads();
    {
        int o = t & 63, kk0 = (t >> 6) * 16;
        #pragma unroll
        for (int j = 0; j < 16; j += 4) {
            float4 v = *(const float4*)&W2[o * 64 + kk0 + j];
            Bs[kk0 + j + 0][o] = v.x;
            Bs[kk0 + j + 1][o] = v.y;
            Bs[kk0 + j + 2][o] = v.z;
            Bs[kk0 + j + 3][o] = v.w;
        }
    }
    #pragma unroll
    for (int p = 0; p < 2; ++p) {
        int row = p * 64 + (t >> 2);
        int w = row >> 5;
        int id = ids[row];
        int q = t & 3;
        const float* src = &P[((size_t)(b * NPTS + id)) * 128 + q * 16];
        #pragma unroll
        for (int j = 0; j < 4; ++j) {
            int c = q * 16 + j * 4;
            float4 v = *(const float4*)&src[j * 4];
            float4 sa = *(const float4*)&scA_s[c];
            float4 ba = *(const float4*)&biA_s[c];
            float4 pd = *(const float4*)&pdd_s[w][c];
            h1T[c + 0][row] = leaky(sa.x * (v.x + pd.x) + ba.x);
            h1T[c + 1][row] = leaky(sa.y * (v.y + pd.y) + ba.y);
            h1T[c + 2][row] = leaky(sa.z * (v.z + pd.z) + ba.z);
            h1T[c + 3][row] = leaky(sa.w * (v.w + pd.w) + ba.w);
        }
    }
    __syncthreads();
    int tx = t & 15, ty = t >> 4;
    float acc[8][4];
    #pragma unroll
    for (int r = 0; r < 8; ++r)
        #pragma unroll
        for (int c = 0; c < 4; ++c) acc[r][c] = 0.f;
    #pragma unroll 4
    for (int kk = 0; kk < 64; ++kk) {
        float4 a0 = *(const float4*)&h1T[kk][ty * 8];
        float4 a1 = *(const float4*)&h1T[kk][ty * 8 + 4];
        float4 bb = *(const float4*)&Bs[kk][tx * 4];
        float av[8] = {a0.x, a0.y, a0.z, a0.w, a1.x, a1.y, a1.z, a1.w};
        #pragma unroll
        for (int r = 0; r < 8; ++r) {
            acc[r][0] += av[r] * bb.x;
            acc[r][1] += av[r] * bb.y;
            acc[r][2] += av[r] * bb.z;
            acc[r][3] += av[r] * bb.w;
        }
    }
    float rm[4];
    #pragma unroll
    for (int c = 0; c < 4; ++c) {
        float m = acc[0][c];
        #pragma unroll
        for (int r = 1; r < 8; ++r) m = fmaxf(m, acc[r][c]);
        rm[c] = m;
    }
    __syncthreads();
    float (*red)[68] = Bs;
    #pragma unroll
    for (int c = 0; c < 4; ++c) red[ty][tx * 4 + c] = rm[c];
    __syncthreads();
    int w = t >> 6, lane = t & 63;
    float m = fmaxf(fmaxf(red[4 * w + 0][lane], red[4 * w + 1][lane]),
                    fmaxf(red[4 * w + 2][lane], red[4 * w + 3][lane]));
    float outv = leaky(sB[lane] * m + bB[lane]);
    xo[((size_t)(b * NPTS + n0 + w)) * 64 + lane] = outv;
    if (xxo != nullptr) {
        float sq = outv * outv;
        #pragma unroll
        for (int d = 32; d; d >>= 1) sq += __shfl_xor(sq, d, 64);
        if (lane == 0) xxo[b * NPTS + n0 + w] = sq;
    }
}

// ---------------- edge layer 3: gather + max, activation hoisted (s5>0) ----------------
__global__ __launch_bounds__(256) void edge3_g_kernel(const float* __restrict__ P,
                                                      const int* __restrict__ idx,
                                                      const float* __restrict__ s5,
                                                      const float* __restrict__ b5,
                                                      float* __restrict__ xo) {
    int t = threadIdx.x, w = t >> 6, lane = t & 63;
    int b = blockIdx.y;
    int n = blockIdx.x * 4 + w;
    int idreg = 0;
    if (lane < 32) idreg = idx[((size_t)(b * NPTS + n)) * KNN + lane];
    float pdd = P[((size_t)(b * NPTS + n)) * 128 + 64 + lane];
    float sc = s5[lane], bi = b5[lane];
    float m = -3.402823466e38f;
    for (int k = 0; k < 32; ++k) {
        int idv = __shfl(idreg, k, 64);
        m = fmaxf(m, P[((size_t)(b * NPTS + idv)) * 128 + lane]);
    }
    xo[((size_t)(b * NPTS + n)) * 64 + lane] = leaky(sc * (m + pdd) + bi);
}

// ---------------- 128x128-tile GEMM for the point-MLP layers ----------------
template <int MODE>
__global__ __launch_bounds__(256) void mlp_gemm(const float* __restrict__ A1,
                                                const float* __restrict__ A2,
                                                const float* __restrict__ A3,
                                                const float* __restrict__ W,
                                                const float* __restrict__ S,
                                                const float* __restrict__ Bi,
                                                const float* __restrict__ gdotv,
                                                float* __restrict__ out,
                                                unsigned* __restrict__ outE) {
    constexpr int KD = (MODE == 2) ? 512 : 192;
    constexpr int ND = (MODE == 0) ? 1024 : (MODE == 1 ? 512 : 256);
    constexpr int WSTR = (MODE == 0) ? 192 : (MODE == 1 ? 1216 : 512);
    constexpr int WOFF = (MODE == 1) ? 1024 : 0;
    __shared__ __align__(16) float As[16][132];
    __shared__ __align__(16) float Bs[16][192];
    int t = threadIdx.x;
    int tx = t & 15, ty = t >> 4;
    int m0 = blockIdx.x * 128, n0 = blockIdx.y * 128;
    float acc[8][8];
    #pragma unroll
    for (int r = 0; r < 8; ++r)
        #pragma unroll
        for (int c = 0; c < 8; ++c) acc[r][c] = 0.f;
    int sm = t >> 1;
    int sk0 = (t & 1) * 8;
    int bc = (sm >> 3) * 12 + (sm & 7);
    for (int k0 = 0; k0 < KD; k0 += 16) {
        const float* Asrc;
        int acol;
        if (MODE == 2) {
            Asrc = A1 + (size_t)(m0 + sm) * 512;
            acol = k0 + sk0;
        } else {
            int sel = k0 >> 6;
            const float* s_ = (sel == 0) ? A1 : (sel == 1 ? A2 : A3);
            Asrc = s_ + (size_t)(m0 + sm) * 64;
            acol = (k0 & 63) + sk0;
        }
        float4 a0 = *(const float4*)&Asrc[acol];
        float4 a1 = *(const float4*)&Asrc[acol + 4];
        float4 b0 = *(const float4*)&W[(size_t)(n0 + sm) * WSTR + WOFF + k0 + sk0];
        float4 b1 = *(const float4*)&W[(size_t)(n0 + sm) * WSTR + WOFF + k0 + sk0 + 4];
        __syncthreads();
        As[sk0 + 0][sm] = a0.x; As[sk0 + 1][sm] = a0.y; As[sk0 + 2][sm] = a0.z; As[sk0 + 3][sm] = a0.w;
        As[sk0 + 4][sm] = a1.x; As[sk0 + 5][sm] = a1.y; As[sk0 + 6][sm] = a1.z; As[sk0 + 7][sm] = a1.w;
        Bs[sk0 + 0][bc] = b0.x; Bs[sk0 + 1][bc] = b0.y; Bs[sk0 + 2][bc] = b0.z; Bs[sk0 + 3][bc] = b0.w;
        Bs[sk0 + 4][bc] = b1.x; Bs[sk0 + 5][bc] = b1.y; Bs[sk0 + 6][bc] = b1.z; Bs[sk0 + 7][bc] = b1.w;
        __syncthreads();
        #pragma unroll
        for (int kk = 0; kk < 16; ++kk) {
            float4 av0 = *(const float4*)&As[kk][ty * 8];
            float4 av1 = *(const float4*)&As[kk][ty * 8 + 4];
            float4 bv0 = *(const float4*)&Bs[kk][tx * 12];
            float4 bv1 = *(const float4*)&Bs[kk][tx * 12 + 4];
            float av[8] = {av0.x, av0.y, av0.z, av0.w, av1.x, av1.y, av1.z, av1.w};
            float bv[8] = {bv0.x, bv0.y, bv0.z, bv0.w, bv1.x, bv1.y, bv1.z, bv1.w};
            #pragma unroll
            for (int r = 0; r < 8; ++r)
                #pragma unroll
                for (int c = 0; c < 8; ++c) acc[r][c] += av[r] * bv[c];
        }
    }
    int b = m0 >> 12;
    if constexpr (MODE == 0) {
        __shared__ float red[16][128];
        float pm[8];
        #pragma unroll
        for (int c = 0; c < 8; ++c) {
            int o = n0 + tx * 8 + c;
            float sc = S[o], bi = Bi[o];
            float gm = -3.402823466e38f;
            #pragma unroll
            for (int r = 0; r < 8; ++r) gm = fmaxf(gm, leaky(sc * acc[r][c] + bi));
            pm[c] = gm;
        }
        __syncthreads();
        #pragma unroll
        for (int c = 0; c < 8; ++c) red[ty][tx * 8 + c] = pm[c];
        __syncthreads();
        if (t < 128) {
            float gm = red[0][t];
            #pragma unroll
            for (int i = 1; i < 16; ++i) gm = fmaxf(gm, red[i][t]);
            atomicMax(&outE[b * 1024 + n0 + t], encf(gm));
        }
    } else {
        #pragma unroll
        for (int r = 0; r < 8; ++r) {
            int m = m0 + ty * 8 + r;
            float4 v0, v1;
            float* vp0 = (float*)&v0;
            float* vp1 = (float*)&v1;
            #pragma unroll
            for (int c = 0; c < 8; ++c) {
                int o = n0 + tx * 8 + c;
                float val = acc[r][c];
                if (MODE == 1) val += gdotv[b * 512 + o];
                float res = leaky(S[o] * val + Bi[o]);
                if (c < 4) vp0[c] = res; else vp1[c - 4] = res;
            }
            *(float4*)&out[(size_t)m * ND + n0 + tx * 8] = v0;
            *(float4*)&out[(size_t)m * ND + n0 + tx * 8 + 4] = v1;
        }
    }
}

// ---------------- gdot[b][o] = sum_c<1024 w7[o][c] * gmax[b][c] ----------------
__global__ __launch_bounds__(256) void gdot_kernel(const unsigned* __restrict__ gmaxE,
                                                   const float* __restrict__ w7,
                                                   float* __restrict__ gdotv) {
    __shared__ float gm[1024];
    int t = threadIdx.x, w = t >> 6, lane = t & 63;
    int b = blockIdx.y;
    int o = blockIdx.x * 4 + w;
    for (int i = t; i < 1024; i += 256) gm[i] = decf(gmaxE[b * 1024 + i]);
    __syncthreads();
    float a = 0.f;
    #pragma unroll
    for (int i = 0; i < 16; ++i) {
        int c = i * 64 + lane;
        a += w7[(size_t)o * 1216 + c] * gm[c];
    }
    #pragma unroll
    for (int d = 32; d; d >>= 1) a += __shfl_xor(a, d, 64);
    if (lane == 0) gdotv[b * 512 + o] = a;
}

// ---------------- final: logits = h256 x w9^T, softmax, transpose out ----------------
__global__ __launch_bounds__(256) void final_kernel(const float* __restrict__ h256,
                                                    const float* __restrict__ w9,
                                                    float* __restrict__ outp) {
    int t = threadIdx.x, w = t >> 6, lane = t & 63;
    int b = blockIdx.y;
    int n = blockIdx.x * 4 + w;
    const float* h = h256 + (size_t)(b * NPTS + n) * 256;
    float a0 = 0.f, a1 = 0.f;
    #pragma unroll
    for (int i = 0; i < 4; ++i) {
        int c = i * 64 + lane;
        float hv = h[c];
        a0 += w9[c] * hv;
        a1 += w9[256 + c] * hv;
    }
    #pragma unroll
    for (int d = 32; d; d >>= 1) {
        a0 += __shfl_xor(a0, d, 64);
        a1 += __shfl_xor(a1, d, 64);
    }
    if (lane == 0) {
        float m = fmaxf(a0, a1);
        float e0 = expf(a0 - m), e1 = expf(a1 - m);
        float s = e0 + e1;
        outp[(size_t)b * 2 * NPTS + n] = e0 / s;
        outp[(size_t)b * 2 * NPTS + NPTS + n] = e1 / s;
    }
}

extern "C" void kernel_launch(void* const* d_in, const int* in_sizes, int n_in,
                              void* d_out, int out_size, void* d_ws, size_t ws_size,
                              hipStream_t stream) {
    (void)in_sizes; (void)n_in; (void)out_size;
    const float* x = (const float*)d_in[0];
    const float* w1 = (const float*)d_in[1];
    const float* w2 = (const float*)d_in[2];
    const float* w3 = (const float*)d_in[3];
    const float* w4 = (const float*)d_in[4];
    const float* w5 = (const float*)d_in[5];
    const float* w6 = (const float*)d_in[6];
    const float* w7 = (const float*)d_in[7];
    const float* w8 = (const float*)d_in[8];
    const float* w9 = (const float*)d_in[9];
    const float* s1 = (const float*)d_in[10]; const float* b1 = (const float*)d_in[11];
    const float* s2 = (const float*)d_in[12]; const float* b2 = (const float*)d_in[13];
    const float* s3 = (const float*)d_in[14]; const float* b3 = (const float*)d_in[15];
    const float* s4 = (const float*)d_in[16]; const float* b4 = (const float*)d_in[17];
    const float* s5 = (const float*)d_in[18]; const float* b5 = (const float*)d_in[19];
    const float* s6 = (const float*)d_in[20]; const float* b6 = (const float*)d_in[21];
    const float* s7 = (const float*)d_in[22]; const float* b7 = (const float*)d_in[23];
    const float* s8 = (const float*)d_in[24]; const float* b8 = (const float*)d_in[25];
    float* out = (float*)d_out;

    // workspace carve-up (floats)
    float* xcl = (float*)d_ws;                       // 131072
    float* x1 = xcl + 131072;                        // 1048576
    float* x2 = x1 + 1048576;                        // 1048576
    float* x3 = x2 + 1048576;                        // 1048576
    float* xxA = x3 + 1048576;                       // 16384
    float* xxB = xxA + 16384;                        // 16384
    float* gdotv = xxB + 16384;                      // 2048
    unsigned* gmaxE = (unsigned*)(gdotv + 2048);     // 4096
    int* idx1 = (int*)(gmaxE + 4096);                // 524288
    int* idx2 = idx1 + 524288;                       // 524288
    int* idx3 = idx2 + 524288;                       // 524288
    float* t512 = (float*)(idx3 + 524288);           // 8388608
    float* h256 = t512 + 8388608;                    // 4194304
    unsigned* Ebuf = (unsigned*)(h256 + 4194304);    // 16777216 per batch slab
    float* Pbuf = t512;                              // alias: P lives in t512

    // 4-batch-wide dist/select if workspace allows 4 E slabs; else per-batch loop.
    const unsigned long long ESTR = 16777216ull;
    size_t need4 = (17471488ull + 4ull * ESTR) * 4ull;
    bool batched = ws_size >= need4;

    hipMemsetAsync(gmaxE, 0, 4096 * sizeof(unsigned), stream);

    txcl_kernel<<<512, 256, 0, stream>>>(x, xcl);
    knn1_kernel<<<dim3(1024, 4), 256, 0, stream>>>(x, idx1);
    qpre_kernel<8><<<512, 256, 0, stream>>>(xcl, w1, Pbuf);
    edge_mm_kernel<<<dim3(1024, 4), 256, 0, stream>>>(Pbuf, idx1, s1, b1, w2, s2, b2, x1, xxA);
    if (batched) {
        dist_gemm_kernel<<<dim3(1024, 4), 256, 0, stream>>>(x1, xxA, Ebuf, 0, ESTR);
        knn_select_kernel<<<dim3(1024, 4), 256, 0, stream>>>(Ebuf, idx2, 0, ESTR);
    } else {
        for (int b = 0; b < 4; ++b) {
            dist_gemm_kernel<<<dim3(1024, 1), 256, 0, stream>>>(x1, xxA, Ebuf, b, 0);
            knn_select_kernel<<<dim3(1024, 1), 256, 0, stream>>>(Ebuf, idx2, b, 0);
        }
    }
    qpre_kernel<64><<<512, 256, 0, stream>>>(x1, w3, Pbuf);
    edge_mm_kernel<<<dim3(1024, 4), 256, 0, stream>>>(Pbuf, idx2, s3, b3, w4, s4, b4, x2, xxB);
    if (batched) {
        dist_gemm_kernel<<<dim3(1024, 4), 256, 0, stream>>>(x2, xxB, Ebuf, 0, ESTR);
        knn_select_kernel<<<dim3(1024, 4), 256, 0, stream>>>(Ebuf, idx3, 0, ESTR);
    } else {
        for (int b = 0; b < 4; ++b) {
            dist_gemm_kernel<<<dim3(1024, 1), 256, 0, stream>>>(x2, xxB, Ebuf, b, 0);
            knn_select_kernel<<<dim3(1024, 1), 256, 0, stream>>>(Ebuf, idx3, b, 0);
        }
    }
    qpre_kernel<64><<<512, 256, 0, stream>>>(x2, w5, Pbuf);
    edge3_g_kernel<<<dim3(1024, 4), 256, 0, stream>>>(Pbuf, idx3, s5, b5, x3);
    mlp_gemm<0><<<dim3(128, 8), 256, 0, stream>>>(x1, x2, x3, w6, s6, b6, nullptr, nullptr, gmaxE);
    gdot_kernel<<<dim3(128, 4), 256, 0, stream>>>(gmaxE, w7, gdotv);
    mlp_gemm<1><<<dim3(128, 4), 256, 0, stream>>>(x1, x2, x3, w7, s7, b7, gdotv, t512, nullptr);
    mlp_gemm<2><<<dim3(128, 2), 256, 0, stream>>>(t512, nullptr, nullptr, w8, s8, b8, nullptr, h256, nullptr);
    final_kernel<<<dim3(1024, 4), 256, 0, stream>>>(h256, w9, out);
}